// Round 6
// baseline (161.051 us; speedup 1.0000x reference)
//
#include <hip/hip_runtime.h>
#include <cstdint>
#include <cstddef>

typedef unsigned short u16;
typedef __attribute__((ext_vector_type(8))) short bf16x8;
typedef __attribute__((ext_vector_type(4))) float f32x4;

#define DEV __device__ __forceinline__

static constexpr float LOG2E = 1.4426950408889634f;

DEV u16 f2bf(float f) {
  uint32_t u = __float_as_uint(f);
  u += 0x7fffu + ((u >> 16) & 1u);
  return (u16)(u >> 16);
}
DEV float bf2f(u16 h) {
  uint32_t u = ((uint32_t)h) << 16;
  return __uint_as_float(u);
}
// packed f32x2 -> bf16x2 (RNE), single VOP3 instr
DEV uint32_t cvtpk(float lo, float hi) {
  uint32_t r;
  asm("v_cvt_pk_bf16_f32 %0, %1, %2" : "=v"(r) : "v"(lo), "v"(hi));
  return r;
}
// 2^x via v_exp_f32 (native exp2)
DEV float exp2fast(float x) {
  float r;
  asm("v_exp_f32 %0, %1" : "=v"(r) : "v"(x));
  return r;
}

DEV f32x4 mfma16(bf16x8 a, bf16x8 b, f32x4 c) {
  return __builtin_amdgcn_mfma_f32_16x16x32_bf16(a, b, c, 0, 0, 0);
}

// async global->LDS, 16B per lane; lds ptr must be wave-uniform
DEV void gload_lds16(const void* g, void* l) {
  __builtin_amdgcn_global_load_lds(
      (const __attribute__((address_space(1))) uint32_t*)g,
      (__attribute__((address_space(3))) uint32_t*)l, 16, 0, 0);
}

static constexpr int BATCH = 4;
static constexpr int C = 256;    // in/out channels
static constexpr int CI = 128;   // inter channels
static constexpr int N = 4096;   // tokens (64x64)

// ---------------- weight convert (q_w pre-scaled by log2e) -----------------
__global__ __launch_bounds__(256) void cvt_w(const float* __restrict__ a,
                                             const float* __restrict__ b,
                                             const float* __restrict__ c,
                                             const float* __restrict__ d,
                                             u16* __restrict__ oa, u16* __restrict__ ob,
                                             u16* __restrict__ oc, u16* __restrict__ od) {
  int i = blockIdx.x * 256 + threadIdx.x;
  oa[i] = f2bf(a[i] * LOG2E);  // Q weights carry the log2e softmax scale
  ob[i] = f2bf(b[i]);
  oc[i] = f2bf(c[i]);
  od[i] = f2bf(d[i]);
}

// ---------------- QKV projection (R3 256-thr form + cvtpk staging) ---------
__global__ __launch_bounds__(256) void proj_kernel(
    const float* __restrict__ x, const float* __restrict__ rgbd,
    const u16* __restrict__ Wq, const u16* __restrict__ Wk, const u16* __restrict__ Wv,
    const float* __restrict__ qb, const float* __restrict__ kb, const float* __restrict__ vb,
    u16* __restrict__ Qb, u16* __restrict__ Kb, u16* __restrict__ Vtb) {
  __shared__ __align__(16) u16 xT[64][C + 8];
  __shared__ __align__(16) u16 rT[64][C + 8];
  const int b = blockIdx.y;
  const int n0 = blockIdx.x * 64;
  const int t = threadIdx.x;
  {
    const int tok = t & 63, cp = (t >> 6) * 2;  // 4 slots x 2 paired channels
    const float* xb = x + (size_t)b * C * N + n0;
    const float* rb = rgbd + (size_t)b * C * N + n0;
    for (int c0 = 0; c0 < C; c0 += 8) {
      int c = c0 + cp;
      *(uint32_t*)&xT[tok][c] = cvtpk(xb[(size_t)c * N + tok], xb[(size_t)(c + 1) * N + tok]);
      *(uint32_t*)&rT[tok][c] = cvtpk(rb[(size_t)c * N + tok], rb[(size_t)(c + 1) * N + tok]);
    }
  }
  __syncthreads();
  const int w = t >> 6, lane = t & 63, g = lane >> 4, cl = lane & 15;

#define PROJ_QK(Sarr, W, bias, Out, SCL)                                              \
  {                                                                                   \
    bf16x8 afr[8];                                                                    \
    _Pragma("unroll") for (int ks = 0; ks < 8; ++ks)                                  \
        afr[ks] = *(const bf16x8*)&Sarr[w * 16 + cl][ks * 32 + g * 8];                \
    _Pragma("unroll") for (int ct = 0; ct < 8; ++ct) {                                \
      f32x4 acc = {0.f, 0.f, 0.f, 0.f};                                               \
      _Pragma("unroll") for (int ks = 0; ks < 8; ++ks) {                              \
        bf16x8 bb = *(const bf16x8*)&W[(size_t)(ct * 16 + cl) * C + ks * 32 + g * 8]; \
        acc = mfma16(afr[ks], bb, acc);                                               \
      }                                                                               \
      float bv = bias[ct * 16 + cl] * (SCL);                                          \
      _Pragma("unroll") for (int r = 0; r < 4; ++r) {                                 \
        int tok = n0 + w * 16 + g * 4 + r;                                            \
        Out[((size_t)b * N + tok) * CI + ct * 16 + cl] = f2bf(acc[r] + bv);           \
      }                                                                               \
    }                                                                                 \
  }

  PROJ_QK(xT, Wq, qb, Qb, LOG2E)
  PROJ_QK(rT, Wk, kb, Kb, 1.0f)
#undef PROJ_QK

  #pragma unroll
  for (int rt = 0; rt < 2; ++rt) {
    bf16x8 aw[8];
    #pragma unroll
    for (int ks = 0; ks < 8; ++ks)
      aw[ks] = *(const bf16x8*)&Wv[(size_t)(w * 32 + rt * 16 + cl) * C + ks * 32 + g * 8];
    #pragma unroll
    for (int ct = 0; ct < 4; ++ct) {
      f32x4 acc = {0.f, 0.f, 0.f, 0.f};
      #pragma unroll
      for (int ks = 0; ks < 8; ++ks) {
        bf16x8 bb = *(const bf16x8*)&rT[ct * 16 + cl][ks * 32 + g * 8];
        acc = mfma16(aw[ks], bb, acc);
      }
      #pragma unroll
      for (int r = 0; r < 4; ++r) {
        int o = w * 32 + rt * 16 + g * 4 + r;
        Vtb[((size_t)b * CI + o) * N + n0 + ct * 16 + cl] = f2bf(acc[r] + vb[o]);
      }
    }
  }
}

// ---------------- flash attention (split-K, 8-wave blocks, 2-phase dbuf) ---
// Grid: 16*B*split blocks (XCD-swizzled). Block = 256 queries x kpb keys;
// 8 waves, 32 q each (2 q-tiles). One staged 32-key K/V tile serves all 8
// waves (halves global streaming vs 4-wave blocks). K/V via global_load_lds
// (source-side XOR swizzle, linear LDS dest). Softmax in exp2-space.
// 2 blocks/CU x 8 waves = 16 waves/CU = 4 waves/SIMD (VGPR-ceiling exact).
__global__ __launch_bounds__(512, 4) void attn_kernel(
    const u16* __restrict__ Qb, const u16* __restrict__ Kb,
    const u16* __restrict__ Vtb, u16* __restrict__ Opart,
    float2* __restrict__ ml, int kpb, int cpx) {
  __shared__ __align__(16) u16 Klds[2][32 * 128];
  __shared__ __align__(16) u16 Vlds[2][128 * 32];
  __shared__ __align__(16) u16 Plds[8][16][40];
  const int lin = blockIdx.x;
  const int nl = (lin & 7) * cpx + (lin >> 3);
  const int qi = nl & 15;   // 16 q-blocks of 256 per (b,s) group
  const int grp = nl >> 4;  // b + 4*s
  const int b = grp & 3;
  const int s = grp >> 2;
  const int q0 = qi * 256;
  const int t = threadIdx.x;
  const int w = t >> 6, lane = t & 63, g = lane >> 4, cl = lane & 15;

  const u16* Kg = Kb + (size_t)b * N * CI;
  const u16* Vg = Vtb + (size_t)b * CI * N;

  // staging source mappings (chunk = 16B), inverse XOR swizzle.
  // 512 threads: 1 K-chunk + 1 V-chunk each.
  const int k_r = t >> 4;                      // K row 0..31
  const int k_ss = (t & 15) ^ (k_r & 15);      // K source chunk
  const int v_r = t >> 2;                      // V row 0..127
  const int v_ss = (t & 3) ^ ((t >> 4) & 3);   // V source chunk
  const int wbase = (t & ~63);                 // wave-uniform chunk base

#define STAGE(bi, k0_)                                                  \
  do {                                                                  \
    gload_lds16(Kg + (size_t)((k0_) + k_r) * CI + k_ss * 8,             \
                &Klds[bi][wbase * 8]);                                  \
    gload_lds16(Vg + (size_t)v_r * N + (k0_) + v_ss * 8,                \
                &Vlds[bi][wbase * 8]);                                  \
  } while (0)

  // hoisted Q B-fragments for both q-tiles (q = cl within tile)
  const u16* Qg = Qb + ((size_t)b * N + q0 + w * 32 + cl) * CI;
  bf16x8 qf[2][4];
  #pragma unroll
  for (int ks = 0; ks < 4; ++ks) {
    qf[0][ks] = *(const bf16x8*)(Qg + ks * 32 + g * 8);
    qf[1][ks] = *(const bf16x8*)(Qg + (size_t)16 * CI + ks * 32 + g * 8);
  }

  f32x4 oacc[2][8];
  #pragma unroll
  for (int qt = 0; qt < 2; ++qt)
    #pragma unroll
    for (int i = 0; i < 8; ++i) oacc[qt][i] = {0.f, 0.f, 0.f, 0.f};
  float m[2] = {-1e30f, -1e30f}, l[2] = {0.f, 0.f};

  const int kbeg = s * kpb, kend = kbeg + kpb;
  STAGE(0, kbeg);
  __syncthreads();

  int buf = 0;
  for (int k0 = kbeg; k0 < kend; k0 += 32) {
    if (k0 + 32 < kend) STAGE(buf ^ 1, k0 + 32);

    // ---- QK^T: S^T[key][q] for both q-tiles ----
    f32x4 st[2][2];
    {
      bf16x8 kf0[4], kf1[4];
      #pragma unroll
      for (int ks = 0; ks < 4; ++ks) {
        kf0[ks] = *(const bf16x8*)&Klds[buf][(cl)*128 + (((ks * 4 + g) ^ cl) & 15) * 8];
        kf1[ks] = *(const bf16x8*)&Klds[buf][(16 + cl) * 128 + (((ks * 4 + g) ^ cl) & 15) * 8];
      }
      f32x4 a00 = {0.f, 0.f, 0.f, 0.f}, a01 = {0.f, 0.f, 0.f, 0.f};
      f32x4 a10 = {0.f, 0.f, 0.f, 0.f}, a11 = {0.f, 0.f, 0.f, 0.f};
      __builtin_amdgcn_s_setprio(1);
      #pragma unroll
      for (int ks = 0; ks < 4; ++ks) {
        a00 = mfma16(kf0[ks], qf[0][ks], a00);
        a01 = mfma16(kf1[ks], qf[0][ks], a01);
        a10 = mfma16(kf0[ks], qf[1][ks], a10);
        a11 = mfma16(kf1[ks], qf[1][ks], a11);
      }
      __builtin_amdgcn_s_setprio(0);
      st[0][0] = a00; st[0][1] = a01;
      st[1][0] = a10; st[1][1] = a11;
    }

    // ---- online softmax per q-tile; Plds reused qt0 -> qt1 ----
    bf16x8 pa[2];
    #pragma unroll
    for (int qt = 0; qt < 2; ++qt) {
      float tmax = st[qt][0][0];
      #pragma unroll
      for (int ct = 0; ct < 2; ++ct)
        #pragma unroll
        for (int r = 0; r < 4; ++r) tmax = fmaxf(tmax, st[qt][ct][r]);
      tmax = fmaxf(tmax, __shfl_xor(tmax, 16));
      tmax = fmaxf(tmax, __shfl_xor(tmax, 32));
      if (!__all(tmax - m[qt] <= 11.5f)) {
        const float mn = fmaxf(m[qt], tmax);
        const float alpha = exp2fast(m[qt] - mn);
        m[qt] = mn;
        l[qt] *= alpha;
        #pragma unroll
        for (int r = 0; r < 4; ++r) {
          float ar = __shfl(alpha, g * 4 + r);
          #pragma unroll
          for (int ct2 = 0; ct2 < 8; ++ct2) oacc[qt][ct2][r] *= ar;
        }
      }
      float ls = 0.f;
      #pragma unroll
      for (int ct = 0; ct < 2; ++ct) {
        float p0 = exp2fast(st[qt][ct][0] - m[qt]);
        float p1 = exp2fast(st[qt][ct][1] - m[qt]);
        float p2 = exp2fast(st[qt][ct][2] - m[qt]);
        float p3 = exp2fast(st[qt][ct][3] - m[qt]);
        ls += (p0 + p1) + (p2 + p3);
        *(uint32_t*)&Plds[w][cl][ct * 16 + g * 4] = cvtpk(p0, p1);
        *(uint32_t*)&Plds[w][cl][ct * 16 + g * 4 + 2] = cvtpk(p2, p3);
      }
      ls += __shfl_xor(ls, 16);
      ls += __shfl_xor(ls, 32);
      l[qt] += ls;
      pa[qt] = *(const bf16x8*)&Plds[w][cl][g * 8];  // read back before qt1 overwrites
    }

    // ---- PV: V-frag read once, used by both q-tiles ----
    __builtin_amdgcn_s_setprio(1);
    #pragma unroll
    for (int ct2 = 0; ct2 < 8; ++ct2) {
      bf16x8 vfr = *(const bf16x8*)&Vlds[buf][(ct2 * 16 + cl) * 32 + ((g ^ (cl >> 2)) & 3) * 8];
      oacc[0][ct2] = mfma16(pa[0], vfr, oacc[0][ct2]);
      oacc[1][ct2] = mfma16(pa[1], vfr, oacc[1][ct2]);
    }
    __builtin_amdgcn_s_setprio(0);

    __syncthreads();
    buf ^= 1;
  }
#undef STAGE

  // epilogue: normalized partial O + (m,l) per q-tile
  #pragma unroll
  for (int qt = 0; qt < 2; ++qt) {
    #pragma unroll
    for (int r = 0; r < 4; ++r) {
      float lr = __shfl(l[qt], g * 4 + r);
      float inv = 1.0f / lr;
      const int q = q0 + w * 32 + qt * 16 + g * 4 + r;
      #pragma unroll
      for (int ct2 = 0; ct2 < 8; ++ct2)
        Opart[(((size_t)(s * BATCH + b)) * N + q) * CI + ct2 * 16 + cl] =
            f2bf(oacc[qt][ct2][r] * inv);
    }
    if (g == 0) {
      const int q = q0 + w * 32 + qt * 16 + cl;
      ml[(size_t)(s * BATCH + b) * N + q] = make_float2(m[qt], l[qt]);
    }
  }
}

// ---------------- split-K combine (compile-time split count) ---------------
template <int NS>
__global__ __launch_bounds__(256) void combine_kernel(
    const u16* __restrict__ Opart, const float2* __restrict__ ml,
    u16* __restrict__ Ob) {
  const int idx = blockIdx.x * 256 + threadIdx.x;  // over B*N*(CI/8)
  const int ci8 = idx & 15;
  const int row = idx >> 4;  // b*N + q
  float2 sv[NS];
  float M = -1e30f;
  #pragma unroll
  for (int sp = 0; sp < NS; ++sp) {
    sv[sp] = ml[(size_t)sp * BATCH * N + row];
    M = fmaxf(M, sv[sp].x);
  }
  float wv[NS], wsum = 0.f;
  #pragma unroll
  for (int sp = 0; sp < NS; ++sp) {
    wv[sp] = sv[sp].y * exp2fast(sv[sp].x - M);
    wsum += wv[sp];
  }
  const float invL = 1.0f / wsum;
  float acc[8];
  #pragma unroll
  for (int j = 0; j < 8; ++j) acc[j] = 0.f;
  #pragma unroll
  for (int sp = 0; sp < NS; ++sp) {
    const float ws = wv[sp] * invL;
    bf16x8 v = *(const bf16x8*)&Opart[((size_t)sp * BATCH * N + row) * CI + ci8 * 8];
    #pragma unroll
    for (int j = 0; j < 8; ++j) acc[j] += ws * bf2f((u16)v[j]);
  }
  bf16x8 o;
  #pragma unroll
  for (int j = 0; j < 8; ++j) o[j] = (short)f2bf(acc[j]);
  *(bf16x8*)&Ob[(size_t)row * CI + ci8 * 8] = o;
}

// ---------------- output projection + residual (R3 64-token form) ----------
__global__ __launch_bounds__(256) void outproj_kernel(
    const u16* __restrict__ Ob, const u16* __restrict__ Wo,
    const float* __restrict__ obias, const float* __restrict__ rgbd,
    float* __restrict__ out) {
  const int b = blockIdx.y;
  const int n0 = blockIdx.x * 64;
  const int t = threadIdx.x;
  const int w = t >> 6, lane = t & 63, g = lane >> 4, cl = lane & 15;

  f32x4 acc[4][4];
  #pragma unroll
  for (int i = 0; i < 4; ++i)
    #pragma unroll
    for (int j = 0; j < 4; ++j) acc[i][j] = {0.f, 0.f, 0.f, 0.f};

  #pragma unroll
  for (int ks = 0; ks < 4; ++ks) {
    bf16x8 bo[4];
    #pragma unroll
    for (int ct = 0; ct < 4; ++ct)
      bo[ct] = *(const bf16x8*)&Ob[((size_t)b * N + n0 + ct * 16 + cl) * CI + ks * 32 + g * 8];
    #pragma unroll
    for (int rt = 0; rt < 4; ++rt) {
      bf16x8 aw = *(const bf16x8*)&Wo[(size_t)(w * 64 + rt * 16 + cl) * CI + ks * 32 + g * 8];
      #pragma unroll
      for (int ct = 0; ct < 4; ++ct) acc[rt][ct] = mfma16(aw, bo[ct], acc[rt][ct]);
    }
  }
  #pragma unroll
  for (int rt = 0; rt < 4; ++rt) {
    #pragma unroll
    for (int r = 0; r < 4; ++r) {
      const int o = w * 64 + rt * 16 + g * 4 + r;
      const float bb = obias[o];
      #pragma unroll
      for (int ct = 0; ct < 4; ++ct) {
        size_t idx = ((size_t)b * C + o) * N + n0 + ct * 16 + cl;
        out[idx] = rgbd[idx] + bb + acc[rt][ct][r];
      }
    }
  }
}

// ---------------- launch ----------------------------------------------------
extern "C" void kernel_launch(void* const* d_in, const int* in_sizes, int n_in,
                              void* d_out, int out_size, void* d_ws, size_t ws_size,
                              hipStream_t stream) {
  (void)in_sizes; (void)n_in; (void)out_size;
  const float* rgbd = (const float*)d_in[0];
  const float* x    = (const float*)d_in[1];
  const float* q_w  = (const float*)d_in[2];
  const float* q_b  = (const float*)d_in[3];
  const float* k_w  = (const float*)d_in[4];
  const float* k_b  = (const float*)d_in[5];
  const float* v_w  = (const float*)d_in[6];
  const float* v_b  = (const float*)d_in[7];
  const float* o_w  = (const float*)d_in[8];
  const float* o_b  = (const float*)d_in[9];
  float* out = (float*)d_out;

  char* ws = (char*)d_ws;
  const size_t MB = 1024 * 1024;
  const size_t szQKV = (size_t)BATCH * N * CI * sizeof(u16);  // 4 MB each
  u16* Qb  = (u16*)(ws);                      // 0..4MB (aliased by Ob later)
  u16* Kb  = (u16*)(ws + szQKV);              // 4..8MB
  u16* Vtb = (u16*)(ws + 2 * szQKV);          // 8..12MB
  u16* Wq  = (u16*)(ws + 3 * szQKV);          // 12..12.25MB
  u16* Wk  = Wq + (size_t)CI * C;
  u16* Wv  = Wk + (size_t)CI * C;
  u16* Wo  = Wv + (size_t)CI * C;
  u16* Opart = (u16*)(ws + 13 * MB);
  // split=8 needs 13 + 32 + 1 = 46MB of ws; fall back to 4 if tight
  const int split = (ws_size >= 46 * MB) ? 8 : 4;
  float2* ml = (float2*)(ws + 13 * MB + (size_t)split * szQKV);
  u16* Ob  = Qb;  // alias: Qb dead after attn

  const int kpb = N / split;
  const int grid_attn = 16 * BATCH * split;  // (N/256) * B * split
  const int cpx = grid_attn / 8;

  cvt_w<<<dim3((C * CI) / 256), 256, 0, stream>>>(q_w, k_w, v_w, o_w, Wq, Wk, Wv, Wo);
  proj_kernel<<<dim3(N / 64, BATCH), 256, 0, stream>>>(x, rgbd, Wq, Wk, Wv,
                                                       q_b, k_b, v_b, Qb, Kb, Vtb);
  attn_kernel<<<dim3(grid_attn), 512, 0, stream>>>(Qb, Kb, Vtb, Opart, ml, kpb, cpx);
  if (split == 8) {
    combine_kernel<8><<<dim3(BATCH * N * (CI / 8) / 256), 256, 0, stream>>>(Opart, ml, Ob);
  } else {
    combine_kernel<4><<<dim3(BATCH * N * (CI / 8) / 256), 256, 0, stream>>>(Opart, ml, Ob);
  }
  outproj_kernel<<<dim3(N / 64, BATCH), 256, 0, stream>>>(Ob, Wo, o_b, rgbd, out);
}

// Round 7
// 106.622 us; speedup vs baseline: 1.5105x; 1.5105x over previous
//
#include <hip/hip_runtime.h>
#include <cstdint>
#include <cstddef>

typedef unsigned short u16;
typedef __attribute__((ext_vector_type(8))) short bf16x8;
typedef __attribute__((ext_vector_type(4))) float f32x4;

#define DEV __device__ __forceinline__

static constexpr float LOG2E = 1.4426950408889634f;

DEV u16 f2bf(float f) {
  uint32_t u = __float_as_uint(f);
  u += 0x7fffu + ((u >> 16) & 1u);
  return (u16)(u >> 16);
}
DEV float bf2f(u16 h) {
  uint32_t u = ((uint32_t)h) << 16;
  return __uint_as_float(u);
}
// packed f32x2 -> bf16x2 (RNE), single VOP3 instr
DEV uint32_t cvtpk(float lo, float hi) {
  uint32_t r;
  asm("v_cvt_pk_bf16_f32 %0, %1, %2" : "=v"(r) : "v"(lo), "v"(hi));
  return r;
}
// 2^x via v_exp_f32 (native exp2)
DEV float exp2fast(float x) {
  float r;
  asm("v_exp_f32 %0, %1" : "=v"(r) : "v"(x));
  return r;
}

DEV f32x4 mfma16(bf16x8 a, bf16x8 b, f32x4 c) {
  return __builtin_amdgcn_mfma_f32_16x16x32_bf16(a, b, c, 0, 0, 0);
}

// async global->LDS, 16B per lane; lds ptr must be wave-uniform
DEV void gload_lds16(const void* g, void* l) {
  __builtin_amdgcn_global_load_lds(
      (const __attribute__((address_space(1))) uint32_t*)g,
      (__attribute__((address_space(3))) uint32_t*)l, 16, 0, 0);
}

static constexpr int BATCH = 4;
static constexpr int C = 256;    // in/out channels
static constexpr int CI = 128;   // inter channels
static constexpr int N = 4096;   // tokens (64x64)
static constexpr int SPLIT = 4;  // key-range split
static constexpr int KPB = N / SPLIT;  // 1024 keys per block
static constexpr int NT = KPB / 32;    // 32 key-tiles per block

// ---------------- weight convert (q_w pre-scaled by log2e) -----------------
__global__ __launch_bounds__(256) void cvt_w(const float* __restrict__ a,
                                             const float* __restrict__ b,
                                             const float* __restrict__ c,
                                             const float* __restrict__ d,
                                             u16* __restrict__ oa, u16* __restrict__ ob,
                                             u16* __restrict__ oc, u16* __restrict__ od) {
  int i = blockIdx.x * 256 + threadIdx.x;
  oa[i] = f2bf(a[i] * LOG2E);  // Q weights carry the log2e softmax scale
  ob[i] = f2bf(b[i]);
  oc[i] = f2bf(c[i]);
  od[i] = f2bf(d[i]);
}

// ---------------- QKV projection (R3 256-thr form + cvtpk staging) ---------
__global__ __launch_bounds__(256) void proj_kernel(
    const float* __restrict__ x, const float* __restrict__ rgbd,
    const u16* __restrict__ Wq, const u16* __restrict__ Wk, const u16* __restrict__ Wv,
    const float* __restrict__ qb, const float* __restrict__ kb, const float* __restrict__ vb,
    u16* __restrict__ Qb, u16* __restrict__ Kb, u16* __restrict__ Vtb) {
  __shared__ __align__(16) u16 xT[64][C + 8];
  __shared__ __align__(16) u16 rT[64][C + 8];
  const int b = blockIdx.y;
  const int n0 = blockIdx.x * 64;
  const int t = threadIdx.x;
  {
    const int tok = t & 63, cp = (t >> 6) * 2;  // 4 slots x 2 paired channels
    const float* xb = x + (size_t)b * C * N + n0;
    const float* rb = rgbd + (size_t)b * C * N + n0;
    for (int c0 = 0; c0 < C; c0 += 8) {
      int c = c0 + cp;
      *(uint32_t*)&xT[tok][c] = cvtpk(xb[(size_t)c * N + tok], xb[(size_t)(c + 1) * N + tok]);
      *(uint32_t*)&rT[tok][c] = cvtpk(rb[(size_t)c * N + tok], rb[(size_t)(c + 1) * N + tok]);
    }
  }
  __syncthreads();
  const int w = t >> 6, lane = t & 63, g = lane >> 4, cl = lane & 15;

#define PROJ_QK(Sarr, W, bias, Out, SCL)                                              \
  {                                                                                   \
    bf16x8 afr[8];                                                                    \
    _Pragma("unroll") for (int ks = 0; ks < 8; ++ks)                                  \
        afr[ks] = *(const bf16x8*)&Sarr[w * 16 + cl][ks * 32 + g * 8];                \
    _Pragma("unroll") for (int ct = 0; ct < 8; ++ct) {                                \
      f32x4 acc = {0.f, 0.f, 0.f, 0.f};                                               \
      _Pragma("unroll") for (int ks = 0; ks < 8; ++ks) {                              \
        bf16x8 bb = *(const bf16x8*)&W[(size_t)(ct * 16 + cl) * C + ks * 32 + g * 8]; \
        acc = mfma16(afr[ks], bb, acc);                                               \
      }                                                                               \
      float bv = bias[ct * 16 + cl] * (SCL);                                          \
      _Pragma("unroll") for (int r = 0; r < 4; ++r) {                                 \
        int tok = n0 + w * 16 + g * 4 + r;                                            \
        Out[((size_t)b * N + tok) * CI + ct * 16 + cl] = f2bf(acc[r] + bv);           \
      }                                                                               \
    }                                                                                 \
  }

  PROJ_QK(xT, Wq, qb, Qb, LOG2E)
  PROJ_QK(rT, Wk, kb, Kb, 1.0f)
#undef PROJ_QK

  #pragma unroll
  for (int rt = 0; rt < 2; ++rt) {
    bf16x8 aw[8];
    #pragma unroll
    for (int ks = 0; ks < 8; ++ks)
      aw[ks] = *(const bf16x8*)&Wv[(size_t)(w * 32 + rt * 16 + cl) * C + ks * 32 + g * 8];
    #pragma unroll
    for (int ct = 0; ct < 4; ++ct) {
      f32x4 acc = {0.f, 0.f, 0.f, 0.f};
      #pragma unroll
      for (int ks = 0; ks < 8; ++ks) {
        bf16x8 bb = *(const bf16x8*)&rT[ct * 16 + cl][ks * 32 + g * 8];
        acc = mfma16(aw[ks], bb, acc);
      }
      #pragma unroll
      for (int r = 0; r < 4; ++r) {
        int o = w * 32 + rt * 16 + g * 4 + r;
        Vtb[((size_t)b * CI + o) * N + n0 + ct * 16 + cl] = f2bf(acc[r] + vb[o]);
      }
    }
  }
}

// ---------------- flash attention: counted-vmcnt dbuf pipeline -------------
// Grid: 1024 blocks (64 q-blocks x B x SPLIT, XCD-swizzled). 4 waves/block,
// 16 q/wave, 64 q/block over KPB keys. K/V 32-key tiles double-buffered via
// global_load_lds (source-side XOR swizzle, linear LDS dest). NO vmcnt(0)
// drain in the loop: raw s_barrier + counted vmcnt(4); stages fly a full
// iteration. 3 barriers/iter: (tile ready) / (K read, overwrite ok) /
// (V read, overwrite ok). kf/vf phases split so VGPR stays <=128 ->
// __launch_bounds__(256,4) = 4 blocks/CU = 16 waves/CU.
__global__ __launch_bounds__(256, 4) void attn_kernel(
    const u16* __restrict__ Qb, const u16* __restrict__ Kb,
    const u16* __restrict__ Vtb, u16* __restrict__ Opart,
    float2* __restrict__ ml) {
  __shared__ __align__(16) u16 Klds[2][32 * 128];
  __shared__ __align__(16) u16 Vlds[2][128 * 32];
  __shared__ __align__(16) u16 Plds[4][16][40];
  // XCD swizzle: 1024 blocks / 8 XCD = 128 nl each = 2 (b,s) groups => ~1MB
  // K/V working set per XCD L2.
  const int lin = blockIdx.x;
  const int nl = (lin & 7) * 128 + (lin >> 3);
  const int qi = nl & 63;
  const int grp = nl >> 6;  // b + 4*s
  const int b = grp & 3;
  const int s = grp >> 2;
  const int q0 = qi * 64;
  const int t = threadIdx.x;
  const int w = t >> 6, lane = t & 63, g = lane >> 4, cl = lane & 15;

  const u16* Kg = Kb + (size_t)b * N * CI;
  const u16* Vg = Vtb + (size_t)b * CI * N;

  // staging source mappings (chunk = 16B), inverse XOR swizzle
  const int k_r = t >> 4;                      // 0..15
  const int k_ss = (t & 15) ^ k_r;
  const int v_r = t >> 2;                      // 0..63
  const int v_ss = (t & 3) ^ ((t >> 4) & 3);
  const int wbase = (t & ~63);

#define STAGE_K(bi, k0_)                                                          \
  do {                                                                            \
    _Pragma("unroll") for (int c = 0; c < 2; ++c) {                               \
      gload_lds16(Kg + (size_t)((k0_) + c * 16 + k_r) * CI + k_ss * 8,            \
                  &Klds[bi][(c * 256 + wbase) * 8]);                              \
    }                                                                             \
  } while (0)
#define STAGE_V(bi, k0_)                                                          \
  do {                                                                            \
    _Pragma("unroll") for (int c = 0; c < 2; ++c) {                               \
      gload_lds16(Vg + (size_t)(c * 64 + v_r) * N + (k0_) + v_ss * 8,             \
                  &Vlds[bi][(c * 256 + wbase) * 8]);                              \
    }                                                                             \
  } while (0)

  // hoisted Q B-fragments (q = cl); drain BEFORE prologue stages so the
  // manual vmcnt accounting below is exact.
  const u16* Qg = Qb + ((size_t)b * N + q0 + w * 16 + cl) * CI;
  bf16x8 qf[4];
  #pragma unroll
  for (int ks = 0; ks < 4; ++ks)
    qf[ks] = *(const bf16x8*)(Qg + ks * 32 + g * 8);
  asm volatile("s_waitcnt vmcnt(0)" ::: "memory");

  f32x4 oacc[8];
  #pragma unroll
  for (int i = 0; i < 8; ++i) oacc[i] = {0.f, 0.f, 0.f, 0.f};
  float m = -1e30f, l = 0.f;

  const int kbeg = s * KPB;
  // prologue: stage tiles 0 and 1 (4 vmem ops each, K then V)
  STAGE_K(0, kbeg);
  STAGE_V(0, kbeg);
  STAGE_K(1, kbeg + 32);
  STAGE_V(1, kbeg + 32);

  int buf = 0;
  for (int tt = 0; tt < NT; ++tt) {
    // Tile tt ready: everything older than the newest 4 vmem ops retired.
    asm volatile("s_waitcnt vmcnt(4)" ::: "memory");
    __builtin_amdgcn_s_barrier();
    const int knext = kbeg + ((tt + 2 < NT) ? tt + 2 : tt) * 32;  // dummy restage keeps count uniform

    // ---- K phase: read fragments, release buffer, restage ----
    bf16x8 kf0[4], kf1[4];
    #pragma unroll
    for (int ks = 0; ks < 4; ++ks) {
      kf0[ks] = *(const bf16x8*)&Klds[buf][(cl)*128 + (((ks * 4 + g) ^ cl) & 15) * 8];
      kf1[ks] = *(const bf16x8*)&Klds[buf][(16 + cl) * 128 + (((ks * 4 + g) ^ cl) & 15) * 8];
    }
    asm volatile("s_waitcnt lgkmcnt(0)" ::: "memory");
    __builtin_amdgcn_s_barrier();
    STAGE_K(buf, knext);

    // ---- QK^T: S^T[key][q] ----
    f32x4 st0 = {0.f, 0.f, 0.f, 0.f}, st1 = {0.f, 0.f, 0.f, 0.f};
    __builtin_amdgcn_s_setprio(1);
    #pragma unroll
    for (int ks = 0; ks < 4; ++ks) {
      st0 = mfma16(kf0[ks], qf[ks], st0);
      st1 = mfma16(kf1[ks], qf[ks], st1);
    }
    __builtin_amdgcn_s_setprio(0);

    // ---- online softmax (exp2-space, defer-max THR=11.5); q = cl ----
    float tmax = st0[0];
    #pragma unroll
    for (int r = 0; r < 4; ++r) tmax = fmaxf(tmax, st0[r]);
    #pragma unroll
    for (int r = 0; r < 4; ++r) tmax = fmaxf(tmax, st1[r]);
    tmax = fmaxf(tmax, __shfl_xor(tmax, 16));
    tmax = fmaxf(tmax, __shfl_xor(tmax, 32));
    if (!__all(tmax - m <= 11.5f)) {
      const float mn = fmaxf(m, tmax);
      const float alpha = exp2fast(m - mn);
      m = mn;
      l *= alpha;
      #pragma unroll
      for (int r = 0; r < 4; ++r) {
        float ar = __shfl(alpha, g * 4 + r);
        #pragma unroll
        for (int ct2 = 0; ct2 < 8; ++ct2) oacc[ct2][r] *= ar;
      }
    }
    float ls = 0.f;
    {
      float p0 = exp2fast(st0[0] - m), p1 = exp2fast(st0[1] - m);
      float p2 = exp2fast(st0[2] - m), p3 = exp2fast(st0[3] - m);
      ls += (p0 + p1) + (p2 + p3);
      *(uint32_t*)&Plds[w][cl][g * 4] = cvtpk(p0, p1);
      *(uint32_t*)&Plds[w][cl][g * 4 + 2] = cvtpk(p2, p3);
      p0 = exp2fast(st1[0] - m); p1 = exp2fast(st1[1] - m);
      p2 = exp2fast(st1[2] - m); p3 = exp2fast(st1[3] - m);
      ls += (p0 + p1) + (p2 + p3);
      *(uint32_t*)&Plds[w][cl][16 + g * 4] = cvtpk(p0, p1);
      *(uint32_t*)&Plds[w][cl][16 + g * 4 + 2] = cvtpk(p2, p3);
    }
    ls += __shfl_xor(ls, 16);
    ls += __shfl_xor(ls, 32);
    l += ls;
    bf16x8 pa = *(const bf16x8*)&Plds[w][cl][g * 8];

    // ---- V phase: read fragments, release buffer, restage ----
    bf16x8 vf[8];
    #pragma unroll
    for (int ct2 = 0; ct2 < 8; ++ct2)
      vf[ct2] = *(const bf16x8*)&Vlds[buf][(ct2 * 16 + cl) * 32 + ((g ^ (cl >> 2)) & 3) * 8];
    asm volatile("s_waitcnt lgkmcnt(0)" ::: "memory");
    __builtin_amdgcn_s_barrier();
    STAGE_V(buf, knext);

    // ---- PV ----
    __builtin_amdgcn_s_setprio(1);
    #pragma unroll
    for (int ct2 = 0; ct2 < 8; ++ct2)
      oacc[ct2] = mfma16(pa, vf[ct2], oacc[ct2]);
    __builtin_amdgcn_s_setprio(0);

    buf ^= 1;
  }
#undef STAGE_K
#undef STAGE_V

  // epilogue: store normalized partial O + (m,l)
  #pragma unroll
  for (int r = 0; r < 4; ++r) {
    float lr = __shfl(l, g * 4 + r);
    float inv = 1.0f / lr;
    const int q = q0 + w * 16 + g * 4 + r;
    #pragma unroll
    for (int ct2 = 0; ct2 < 8; ++ct2)
      Opart[(((size_t)(s * BATCH + b)) * N + q) * CI + ct2 * 16 + cl] =
          f2bf(oacc[ct2][r] * inv);
  }
  if (g == 0) {
    const int q = q0 + w * 16 + cl;
    ml[(size_t)(s * BATCH + b) * N + q] = make_float2(m, l);
  }
}

// ---------------- split-K combine (exp2-space weights) ---------------------
template <int NS>
__global__ __launch_bounds__(256) void combine_kernel(
    const u16* __restrict__ Opart, const float2* __restrict__ ml,
    u16* __restrict__ Ob) {
  const int idx = blockIdx.x * 256 + threadIdx.x;  // over B*N*(CI/8)
  const int ci8 = idx & 15;
  const int row = idx >> 4;  // b*N + q
  float2 sv[NS];
  float M = -1e30f;
  #pragma unroll
  for (int sp = 0; sp < NS; ++sp) {
    sv[sp] = ml[(size_t)sp * BATCH * N + row];
    M = fmaxf(M, sv[sp].x);
  }
  float wv[NS], wsum = 0.f;
  #pragma unroll
  for (int sp = 0; sp < NS; ++sp) {
    wv[sp] = sv[sp].y * exp2fast(sv[sp].x - M);
    wsum += wv[sp];
  }
  const float invL = 1.0f / wsum;
  float acc[8];
  #pragma unroll
  for (int j = 0; j < 8; ++j) acc[j] = 0.f;
  #pragma unroll
  for (int sp = 0; sp < NS; ++sp) {
    const float ws = wv[sp] * invL;
    bf16x8 v = *(const bf16x8*)&Opart[((size_t)sp * BATCH * N + row) * CI + ci8 * 8];
    #pragma unroll
    for (int j = 0; j < 8; ++j) acc[j] += ws * bf2f((u16)v[j]);
  }
  bf16x8 o;
  #pragma unroll
  for (int j = 0; j < 8; ++j) o[j] = (short)f2bf(acc[j]);
  *(bf16x8*)&Ob[(size_t)row * CI + ci8 * 8] = o;
}

// ---------------- output projection + residual (R3 64-token form) ----------
__global__ __launch_bounds__(256) void outproj_kernel(
    const u16* __restrict__ Ob, const u16* __restrict__ Wo,
    const float* __restrict__ obias, const float* __restrict__ rgbd,
    float* __restrict__ out) {
  const int b = blockIdx.y;
  const int n0 = blockIdx.x * 64;
  const int t = threadIdx.x;
  const int w = t >> 6, lane = t & 63, g = lane >> 4, cl = lane & 15;

  f32x4 acc[4][4];
  #pragma unroll
  for (int i = 0; i < 4; ++i)
    #pragma unroll
    for (int j = 0; j < 4; ++j) acc[i][j] = {0.f, 0.f, 0.f, 0.f};

  #pragma unroll
  for (int ks = 0; ks < 4; ++ks) {
    bf16x8 bo[4];
    #pragma unroll
    for (int ct = 0; ct < 4; ++ct)
      bo[ct] = *(const bf16x8*)&Ob[((size_t)b * N + n0 + ct * 16 + cl) * CI + ks * 32 + g * 8];
    #pragma unroll
    for (int rt = 0; rt < 4; ++rt) {
      bf16x8 aw = *(const bf16x8*)&Wo[(size_t)(w * 64 + rt * 16 + cl) * CI + ks * 32 + g * 8];
      #pragma unroll
      for (int ct = 0; ct < 4; ++ct) acc[rt][ct] = mfma16(aw, bo[ct], acc[rt][ct]);
    }
  }
  #pragma unroll
  for (int rt = 0; rt < 4; ++rt) {
    #pragma unroll
    for (int r = 0; r < 4; ++r) {
      const int o = w * 64 + rt * 16 + g * 4 + r;
      const float bb = obias[o];
      #pragma unroll
      for (int ct = 0; ct < 4; ++ct) {
        size_t idx = ((size_t)b * C + o) * N + n0 + ct * 16 + cl;
        out[idx] = rgbd[idx] + bb + acc[rt][ct][r];
      }
    }
  }
}

// ---------------- launch ----------------------------------------------------
extern "C" void kernel_launch(void* const* d_in, const int* in_sizes, int n_in,
                              void* d_out, int out_size, void* d_ws, size_t ws_size,
                              hipStream_t stream) {
  (void)in_sizes; (void)n_in; (void)out_size; (void)ws_size;
  const float* rgbd = (const float*)d_in[0];
  const float* x    = (const float*)d_in[1];
  const float* q_w  = (const float*)d_in[2];
  const float* q_b  = (const float*)d_in[3];
  const float* k_w  = (const float*)d_in[4];
  const float* k_b  = (const float*)d_in[5];
  const float* v_w  = (const float*)d_in[6];
  const float* v_b  = (const float*)d_in[7];
  const float* o_w  = (const float*)d_in[8];
  const float* o_b  = (const float*)d_in[9];
  float* out = (float*)d_out;

  char* ws = (char*)d_ws;
  const size_t MB = 1024 * 1024;
  const size_t szQKV = (size_t)BATCH * N * CI * sizeof(u16);  // 4 MB each
  u16* Qb  = (u16*)(ws);                      // 0..4MB (aliased by Ob later)
  u16* Kb  = (u16*)(ws + szQKV);              // 4..8MB
  u16* Vtb = (u16*)(ws + 2 * szQKV);          // 8..12MB
  u16* Wq  = (u16*)(ws + 3 * szQKV);          // 12..12.25MB
  u16* Wk  = Wq + (size_t)CI * C;
  u16* Wv  = Wk + (size_t)CI * C;
  u16* Wo  = Wv + (size_t)CI * C;
  u16* Opart = (u16*)(ws + 13 * MB);          // 13..29MB (SPLIT*4MB)
  float2* ml = (float2*)(ws + 29 * MB);       // 29..29.5MB
  u16* Ob  = Qb;  // alias: Qb dead after attn

  const int grid_attn = 64 * BATCH * SPLIT;  // (N/64) * B * SPLIT = 1024

  cvt_w<<<dim3((C * CI) / 256), 256, 0, stream>>>(q_w, k_w, v_w, o_w, Wq, Wk, Wv, Wo);
  proj_kernel<<<dim3(N / 64, BATCH), 256, 0, stream>>>(x, rgbd, Wq, Wk, Wv,
                                                       q_b, k_b, v_b, Qb, Kb, Vtb);
  attn_kernel<<<dim3(grid_attn), 256, 0, stream>>>(Qb, Kb, Vtb, Opart, ml);
  combine_kernel<SPLIT><<<dim3(BATCH * N * (CI / 8) / 256), 256, 0, stream>>>(Opart, ml, Ob);
  outproj_kernel<<<dim3(N / 64, BATCH), 256, 0, stream>>>(Ob, Wo, o_b, rgbd, out);
}

// Round 8
// 94.851 us; speedup vs baseline: 1.6979x; 1.1241x over previous
//
#include <hip/hip_runtime.h>
#include <cstdint>
#include <cstddef>

typedef unsigned short u16;
typedef __attribute__((ext_vector_type(8))) short bf16x8;
typedef __attribute__((ext_vector_type(4))) float f32x4;
typedef __attribute__((ext_vector_type(16))) float f32x16;
typedef __attribute__((ext_vector_type(4))) uint32_t u32x4;

#define DEV __device__ __forceinline__

static constexpr float LOG2E = 1.4426950408889634f;

DEV u16 f2bf(float f) {
  uint32_t u = __float_as_uint(f);
  u += 0x7fffu + ((u >> 16) & 1u);
  return (u16)(u >> 16);
}
DEV float bf2f(u16 h) {
  uint32_t u = ((uint32_t)h) << 16;
  return __uint_as_float(u);
}
// packed f32x2 -> bf16x2 (RNE), single VOP3 instr
DEV uint32_t cvtpk(float lo, float hi) {
  uint32_t r;
  asm("v_cvt_pk_bf16_f32 %0, %1, %2" : "=v"(r) : "v"(lo), "v"(hi));
  return r;
}
// 2^x via v_exp_f32 (native exp2)
DEV float exp2fast(float x) {
  float r;
  asm("v_exp_f32 %0, %1" : "=v"(r) : "v"(x));
  return r;
}
// swap a[lanes 32..63] <-> b[lanes 0..31]
DEV void plswap(uint32_t& a, uint32_t& b) {
  asm("v_permlane32_swap_b32 %0, %1" : "+v"(a), "+v"(b));
}

DEV f32x4 mfma16(bf16x8 a, bf16x8 b, f32x4 c) {
  return __builtin_amdgcn_mfma_f32_16x16x32_bf16(a, b, c, 0, 0, 0);
}
DEV f32x16 mfma32(bf16x8 a, bf16x8 b, f32x16 c) {
  return __builtin_amdgcn_mfma_f32_32x32x16_bf16(a, b, c, 0, 0, 0);
}

// async global->LDS, 16B per lane; lds ptr must be wave-uniform
DEV void gload_lds16(const void* g, void* l) {
  __builtin_amdgcn_global_load_lds(
      (const __attribute__((address_space(1))) uint32_t*)g,
      (__attribute__((address_space(3))) uint32_t*)l, 16, 0, 0);
}

static constexpr int BATCH = 4;
static constexpr int C = 256;    // in/out channels
static constexpr int CI = 128;   // inter channels
static constexpr int N = 4096;   // tokens (64x64)
static constexpr int SPLIT = 4;  // key-range split
static constexpr int KPB = N / SPLIT;  // 1024 keys per block
static constexpr int NT = KPB / 32;    // 32 key-tiles per block

// ---------------- weight convert (q_w pre-scaled by log2e) -----------------
__global__ __launch_bounds__(256) void cvt_w(const float* __restrict__ a,
                                             const float* __restrict__ b,
                                             const float* __restrict__ c,
                                             const float* __restrict__ d,
                                             u16* __restrict__ oa, u16* __restrict__ ob,
                                             u16* __restrict__ oc, u16* __restrict__ od) {
  int i = blockIdx.x * 256 + threadIdx.x;
  oa[i] = f2bf(a[i] * LOG2E);  // Q weights carry the log2e softmax scale
  ob[i] = f2bf(b[i]);
  oc[i] = f2bf(c[i]);
  od[i] = f2bf(d[i]);
}

// ---------------- QKV projection (unchanged; passed) -----------------------
__global__ __launch_bounds__(256) void proj_kernel(
    const float* __restrict__ x, const float* __restrict__ rgbd,
    const u16* __restrict__ Wq, const u16* __restrict__ Wk, const u16* __restrict__ Wv,
    const float* __restrict__ qb, const float* __restrict__ kb, const float* __restrict__ vb,
    u16* __restrict__ Qb, u16* __restrict__ Kb, u16* __restrict__ Vtb) {
  __shared__ __align__(16) u16 xT[64][C + 8];
  __shared__ __align__(16) u16 rT[64][C + 8];
  const int b = blockIdx.y;
  const int n0 = blockIdx.x * 64;
  const int t = threadIdx.x;
  {
    const int tok = t & 63, cp = (t >> 6) * 2;
    const float* xb = x + (size_t)b * C * N + n0;
    const float* rb = rgbd + (size_t)b * C * N + n0;
    for (int c0 = 0; c0 < C; c0 += 8) {
      int c = c0 + cp;
      *(uint32_t*)&xT[tok][c] = cvtpk(xb[(size_t)c * N + tok], xb[(size_t)(c + 1) * N + tok]);
      *(uint32_t*)&rT[tok][c] = cvtpk(rb[(size_t)c * N + tok], rb[(size_t)(c + 1) * N + tok]);
    }
  }
  __syncthreads();
  const int w = t >> 6, lane = t & 63, g = lane >> 4, cl = lane & 15;

#define PROJ_QK(Sarr, W, bias, Out, SCL)                                              \
  {                                                                                   \
    bf16x8 afr[8];                                                                    \
    _Pragma("unroll") for (int ks = 0; ks < 8; ++ks)                                  \
        afr[ks] = *(const bf16x8*)&Sarr[w * 16 + cl][ks * 32 + g * 8];                \
    _Pragma("unroll") for (int ct = 0; ct < 8; ++ct) {                                \
      f32x4 acc = {0.f, 0.f, 0.f, 0.f};                                               \
      _Pragma("unroll") for (int ks = 0; ks < 8; ++ks) {                              \
        bf16x8 bb = *(const bf16x8*)&W[(size_t)(ct * 16 + cl) * C + ks * 32 + g * 8]; \
        acc = mfma16(afr[ks], bb, acc);                                               \
      }                                                                               \
      float bv = bias[ct * 16 + cl] * (SCL);                                          \
      _Pragma("unroll") for (int r = 0; r < 4; ++r) {                                 \
        int tok = n0 + w * 16 + g * 4 + r;                                            \
        Out[((size_t)b * N + tok) * CI + ct * 16 + cl] = f2bf(acc[r] + bv);           \
      }                                                                               \
    }                                                                                 \
  }

  PROJ_QK(xT, Wq, qb, Qb, LOG2E)
  PROJ_QK(rT, Wk, kb, Kb, 1.0f)
#undef PROJ_QK

  #pragma unroll
  for (int rt = 0; rt < 2; ++rt) {
    bf16x8 aw[8];
    #pragma unroll
    for (int ks = 0; ks < 8; ++ks)
      aw[ks] = *(const bf16x8*)&Wv[(size_t)(w * 32 + rt * 16 + cl) * C + ks * 32 + g * 8];
    #pragma unroll
    for (int ct = 0; ct < 4; ++ct) {
      f32x4 acc = {0.f, 0.f, 0.f, 0.f};
      #pragma unroll
      for (int ks = 0; ks < 8; ++ks) {
        bf16x8 bb = *(const bf16x8*)&rT[ct * 16 + cl][ks * 32 + g * 8];
        acc = mfma16(aw[ks], bb, acc);
      }
      #pragma unroll
      for (int r = 0; r < 4; ++r) {
        int o = w * 32 + rt * 16 + g * 4 + r;
        Vtb[((size_t)b * CI + o) * N + n0 + ct * 16 + cl] = f2bf(acc[r] + vb[o]);
      }
    }
  }
}

// ---------------- flash attention: 32x32 MFMA + in-register P --------------
// Grid: 512 blocks (32 q-blocks x B x SPLIT, XCD-swizzled), 4 waves/block,
// 32 q/wave (128 q/block) over KPB keys. Swapped QK^T with 32x32x16 MFMA:
// S^T C-layout (col=lane&31=q, row=crow(reg,hi)) -> softmax fully in-lane
// (16 keys/lane + one shfl_xor(32)); P converts to the PV A-fragment with
// 8 cvtpk + 4 v_permlane32_swap (NO LDS for P). K LDS chunk-swizzle
// c^(key&15), V c^((ci>>1)&3): both reads <=2-way (free). Counted-vmcnt
// 3-barrier dbuf schedule from R7 kept.
__global__ __launch_bounds__(256, 2) void attn_kernel(
    const u16* __restrict__ Qb, const u16* __restrict__ Kb,
    const u16* __restrict__ Vtb, u16* __restrict__ Opart,
    float2* __restrict__ ml) {
  __shared__ __align__(16) u16 Klds[2][32 * 128];  // [key][ci], swizzled chunks
  __shared__ __align__(16) u16 Vlds[2][128 * 32];  // [ci][key], swizzled chunks
  const int lin = blockIdx.x;
  const int nl = (lin & 7) * 64 + (lin >> 3);  // 512 blocks / 8 XCDs
  const int qi = nl & 31;
  const int grp = nl >> 5;  // b + 4*s
  const int b = grp & 3;
  const int s = grp >> 2;
  const int q0 = qi * 128;
  const int t = threadIdx.x;
  const int w = t >> 6, lane = t & 63;
  const int hi = lane >> 5, l31 = lane & 31;

  const u16* Kg = Kb + (size_t)b * N * CI;
  const u16* Vg = Vtb + (size_t)b * CI * N;

  // staging source mappings (chunk = 16B), inverse XOR swizzle
  const int k_r = t >> 4;                      // 0..15 (row within segment)
  const int k_ss = (t & 15) ^ k_r;             // K: c ^ (key&15)
  const int v_r = t >> 2;                      // 0..63 (ci within segment)
  const int v_ss = (t & 3) ^ ((t >> 3) & 3);   // V: c ^ ((ci>>1)&3)
  const int wbase = (t & ~63);

#define STAGE_K(bi, k0_)                                                          \
  do {                                                                            \
    _Pragma("unroll") for (int c = 0; c < 2; ++c) {                               \
      gload_lds16(Kg + (size_t)((k0_) + c * 16 + k_r) * CI + k_ss * 8,            \
                  &Klds[bi][(c * 256 + wbase) * 8]);                              \
    }                                                                             \
  } while (0)
#define STAGE_V(bi, k0_)                                                          \
  do {                                                                            \
    _Pragma("unroll") for (int c = 0; c < 2; ++c) {                               \
      gload_lds16(Vg + (size_t)(c * 64 + v_r) * N + (k0_) + v_ss * 8,             \
                  &Vlds[bi][(c * 256 + wbase) * 8]);                              \
    }                                                                             \
  } while (0)

  // hoisted Q B-fragments: lane holds Q[q0+w*32+l31][ci 16m+8hi .. +7]
  const u16* Qg = Qb + ((size_t)b * N + q0 + w * 32 + l31) * CI;
  bf16x8 qf[8];
  #pragma unroll
  for (int mm = 0; mm < 8; ++mm)
    qf[mm] = *(const bf16x8*)(Qg + mm * 16 + hi * 8);
  asm volatile("s_waitcnt vmcnt(0)" ::: "memory");

  f32x16 oacc[4];
  #pragma unroll
  for (int ct = 0; ct < 4; ++ct)
    #pragma unroll
    for (int i = 0; i < 16; ++i) oacc[ct][i] = 0.f;
  float m_run = -1e30f, l_run = 0.f;

  const int kbeg = s * KPB;
  STAGE_K(0, kbeg);
  STAGE_V(0, kbeg);
  STAGE_K(1, kbeg + 32);
  STAGE_V(1, kbeg + 32);

  int buf = 0;
  for (int tt = 0; tt < NT; ++tt) {
    asm volatile("s_waitcnt vmcnt(4)" ::: "memory");
    __builtin_amdgcn_s_barrier();
    const int knext = kbeg + ((tt + 2 < NT) ? tt + 2 : tt) * 32;  // dummy tail restage

    // ---- K phase: A-frags K[key=l31][ci 16m+8hi ..+7], swizzled chunk ----
    bf16x8 kf[8];
    #pragma unroll
    for (int mm = 0; mm < 8; ++mm)
      kf[mm] = *(const bf16x8*)&Klds[buf][l31 * 128 + ((((mm << 1) | hi) ^ l31) & 15) * 8];
    asm volatile("s_waitcnt lgkmcnt(0)" ::: "memory");
    __builtin_amdgcn_s_barrier();
    STAGE_K(buf, knext);

    // ---- QK^T: S^T[key][q] = mfma32(K, Q), K-dim = 128 ci over 8 mfma ----
    f32x16 st;
    #pragma unroll
    for (int i = 0; i < 16; ++i) st[i] = 0.f;
    __builtin_amdgcn_s_setprio(1);
    #pragma unroll
    for (int mm = 0; mm < 8; ++mm) st = mfma32(kf[mm], qf[mm], st);
    __builtin_amdgcn_s_setprio(0);

    // ---- online softmax: lane owns q = l31; 16 key-slots in-lane ----
    float tmax = st[0];
    #pragma unroll
    for (int i = 1; i < 16; ++i) tmax = fmaxf(tmax, st[i]);
    tmax = fmaxf(tmax, __shfl_xor(tmax, 32));
    if (!__all(tmax - m_run <= 11.5f)) {
      const float mn = fmaxf(m_run, tmax);
      const float alpha = exp2fast(m_run - mn);
      m_run = mn;
      l_run *= alpha;
      #pragma unroll
      for (int reg = 0; reg < 16; ++reg) {
        float ar = __shfl(alpha, (reg & 3) + 8 * (reg >> 2) + 4 * hi);
        oacc[0][reg] *= ar; oacc[1][reg] *= ar;
        oacc[2][reg] *= ar; oacc[3][reg] *= ar;
      }
    }
    float p[16];
    float ls = 0.f;
    #pragma unroll
    for (int i = 0; i < 16; ++i) {
      p[i] = exp2fast(st[i] - m_run);
      ls += p[i];
    }
    ls += __shfl_xor(ls, 32);
    l_run += ls;

    // ---- P -> PV A-fragment in-register (cvtpk + permlane32_swap) ----
    uint32_t d0 = cvtpk(p[0], p[1]),  e0 = cvtpk(p[4], p[5]);
    uint32_t d1 = cvtpk(p[2], p[3]),  e1 = cvtpk(p[6], p[7]);
    uint32_t d2 = cvtpk(p[8], p[9]),  e2 = cvtpk(p[12], p[13]);
    uint32_t d3 = cvtpk(p[10], p[11]), e3 = cvtpk(p[14], p[15]);
    plswap(d0, e0);
    plswap(d1, e1);
    plswap(d2, e2);
    plswap(d3, e3);
    u32x4 pw0 = {d0, d1, e0, e1};  // keys 16*0 + 8hi .. (A rows = q)
    u32x4 pw1 = {d2, d3, e2, e3};  // keys 16*1 + 8hi ..
    bf16x8 pa0 = __builtin_bit_cast(bf16x8, pw0);
    bf16x8 pa1 = __builtin_bit_cast(bf16x8, pw1);

    // ---- V phase: B-frags V[key 16ks+8hi ..+7][ci=32ct+l31] ----
    bf16x8 vf[4][2];
    const int vsw = (l31 >> 1) & 3;
    #pragma unroll
    for (int ct = 0; ct < 4; ++ct)
      #pragma unroll
      for (int ks = 0; ks < 2; ++ks)
        vf[ct][ks] = *(const bf16x8*)
            &Vlds[buf][(32 * ct + l31) * 32 + ((((ks << 1) | hi) ^ vsw) & 3) * 8];
    asm volatile("s_waitcnt lgkmcnt(0)" ::: "memory");
    __builtin_amdgcn_s_barrier();
    STAGE_V(buf, knext);

    // ---- PV: O[q][ci] += P x V ----
    __builtin_amdgcn_s_setprio(1);
    #pragma unroll
    for (int ct = 0; ct < 4; ++ct) {
      oacc[ct] = mfma32(pa0, vf[ct][0], oacc[ct]);
      oacc[ct] = mfma32(pa1, vf[ct][1], oacc[ct]);
    }
    __builtin_amdgcn_s_setprio(0);

    buf ^= 1;
  }
#undef STAGE_K
#undef STAGE_V
  asm volatile("s_waitcnt vmcnt(0)" ::: "memory");  // drain dummy restages

  // epilogue: normalized partial O + (m,l); oacc[ct][reg] is
  // O[q = q0+w*32+crow(reg,hi)][ci = 32ct+l31]
  const float inv = 1.0f / l_run;
  #pragma unroll
  for (int reg = 0; reg < 16; ++reg) {
    const int ql = (reg & 3) + 8 * (reg >> 2) + 4 * hi;
    const float invr = __shfl(inv, ql);
    const int q = q0 + w * 32 + ql;
    #pragma unroll
    for (int ct = 0; ct < 4; ++ct)
      Opart[(((size_t)(s * BATCH + b)) * N + q) * CI + 32 * ct + l31] =
          f2bf(oacc[ct][reg] * invr);
  }
  if (lane < 32) {
    const int q = q0 + w * 32 + lane;
    ml[(size_t)(s * BATCH + b) * N + q] = make_float2(m_run, l_run);
  }
}

// ---------------- split-K combine (exp2-space weights) ---------------------
template <int NS>
__global__ __launch_bounds__(256) void combine_kernel(
    const u16* __restrict__ Opart, const float2* __restrict__ ml,
    u16* __restrict__ Ob) {
  const int idx = blockIdx.x * 256 + threadIdx.x;  // over B*N*(CI/8)
  const int ci8 = idx & 15;
  const int row = idx >> 4;  // b*N + q
  float2 sv[NS];
  float M = -1e30f;
  #pragma unroll
  for (int sp = 0; sp < NS; ++sp) {
    sv[sp] = ml[(size_t)sp * BATCH * N + row];
    M = fmaxf(M, sv[sp].x);
  }
  float wv[NS], wsum = 0.f;
  #pragma unroll
  for (int sp = 0; sp < NS; ++sp) {
    wv[sp] = sv[sp].y * exp2fast(sv[sp].x - M);
    wsum += wv[sp];
  }
  const float invL = 1.0f / wsum;
  float acc[8];
  #pragma unroll
  for (int j = 0; j < 8; ++j) acc[j] = 0.f;
  #pragma unroll
  for (int sp = 0; sp < NS; ++sp) {
    const float ws = wv[sp] * invL;
    bf16x8 v = *(const bf16x8*)&Opart[((size_t)sp * BATCH * N + row) * CI + ci8 * 8];
    #pragma unroll
    for (int j = 0; j < 8; ++j) acc[j] += ws * bf2f((u16)v[j]);
  }
  bf16x8 o;
  #pragma unroll
  for (int j = 0; j < 8; ++j) o[j] = (short)f2bf(acc[j]);
  *(bf16x8*)&Ob[(size_t)row * CI + ci8 * 8] = o;
}

// ---------------- output projection + residual -----------------------------
__global__ __launch_bounds__(256) void outproj_kernel(
    const u16* __restrict__ Ob, const u16* __restrict__ Wo,
    const float* __restrict__ obias, const float* __restrict__ rgbd,
    float* __restrict__ out) {
  const int b = blockIdx.y;
  const int n0 = blockIdx.x * 64;
  const int t = threadIdx.x;
  const int w = t >> 6, lane = t & 63, g = lane >> 4, cl = lane & 15;

  f32x4 acc[4][4];
  #pragma unroll
  for (int i = 0; i < 4; ++i)
    #pragma unroll
    for (int j = 0; j < 4; ++j) acc[i][j] = {0.f, 0.f, 0.f, 0.f};

  #pragma unroll
  for (int ks = 0; ks < 4; ++ks) {
    bf16x8 bo[4];
    #pragma unroll
    for (int ct = 0; ct < 4; ++ct)
      bo[ct] = *(const bf16x8*)&Ob[((size_t)b * N + n0 + ct * 16 + cl) * CI + ks * 32 + g * 8];
    #pragma unroll
    for (int rt = 0; rt < 4; ++rt) {
      bf16x8 aw = *(const bf16x8*)&Wo[(size_t)(w * 64 + rt * 16 + cl) * CI + ks * 32 + g * 8];
      #pragma unroll
      for (int ct = 0; ct < 4; ++ct) acc[rt][ct] = mfma16(aw, bo[ct], acc[rt][ct]);
    }
  }
  #pragma unroll
  for (int rt = 0; rt < 4; ++rt) {
    #pragma unroll
    for (int r = 0; r < 4; ++r) {
      const int o = w * 64 + rt * 16 + g * 4 + r;
      const float bb = obias[o];
      #pragma unroll
      for (int ct = 0; ct < 4; ++ct) {
        size_t idx = ((size_t)b * C + o) * N + n0 + ct * 16 + cl;
        out[idx] = rgbd[idx] + bb + acc[rt][ct][r];
      }
    }
  }
}

// ---------------- launch ----------------------------------------------------
extern "C" void kernel_launch(void* const* d_in, const int* in_sizes, int n_in,
                              void* d_out, int out_size, void* d_ws, size_t ws_size,
                              hipStream_t stream) {
  (void)in_sizes; (void)n_in; (void)out_size; (void)ws_size;
  const float* rgbd = (const float*)d_in[0];
  const float* x    = (const float*)d_in[1];
  const float* q_w  = (const float*)d_in[2];
  const float* q_b  = (const float*)d_in[3];
  const float* k_w  = (const float*)d_in[4];
  const float* k_b  = (const float*)d_in[5];
  const float* v_w  = (const float*)d_in[6];
  const float* v_b  = (const float*)d_in[7];
  const float* o_w  = (const float*)d_in[8];
  const float* o_b  = (const float*)d_in[9];
  float* out = (float*)d_out;

  char* ws = (char*)d_ws;
  const size_t MB = 1024 * 1024;
  const size_t szQKV = (size_t)BATCH * N * CI * sizeof(u16);  // 4 MB each
  u16* Qb  = (u16*)(ws);                      // 0..4MB (aliased by Ob later)
  u16* Kb  = (u16*)(ws + szQKV);              // 4..8MB
  u16* Vtb = (u16*)(ws + 2 * szQKV);          // 8..12MB
  u16* Wq  = (u16*)(ws + 3 * szQKV);          // 12..12.25MB
  u16* Wk  = Wq + (size_t)CI * C;
  u16* Wv  = Wk + (size_t)CI * C;
  u16* Wo  = Wv + (size_t)CI * C;
  u16* Opart = (u16*)(ws + 13 * MB);          // 13..29MB (SPLIT*4MB)
  float2* ml = (float2*)(ws + 29 * MB);       // 29..29.5MB
  u16* Ob  = Qb;  // alias: Qb dead after attn

  const int grid_attn = 32 * BATCH * SPLIT;  // (N/128) * B * SPLIT = 512

  cvt_w<<<dim3((C * CI) / 256), 256, 0, stream>>>(q_w, k_w, v_w, o_w, Wq, Wk, Wv, Wo);
  proj_kernel<<<dim3(N / 64, BATCH), 256, 0, stream>>>(x, rgbd, Wq, Wk, Wv,
                                                       q_b, k_b, v_b, Qb, Kb, Vtb);
  attn_kernel<<<dim3(grid_attn), 256, 0, stream>>>(Qb, Kb, Vtb, Opart, ml);
  combine_kernel<SPLIT><<<dim3(BATCH * N * (CI / 8) / 256), 256, 0, stream>>>(Opart, ml, Ob);
  outproj_kernel<<<dim3(N / 64, BATCH), 256, 0, stream>>>(Ob, Wo, o_b, rgbd, out);
}